// Round 11
// baseline (117.373 us; speedup 1.0000x reference)
//
#include <hip/hip_runtime.h>
#include <hip/hip_fp16.h>

#define LSIDE 128
#define NB 16

union P8 { __half h[8]; int4 v; };

// packed8[z][y][x] = fp16 {v000,v001,v010,v011,v100,v101,v110,v111}
__global__ __launch_bounds__(256) void pack8_kernel(
    const float* __restrict__ vol, int4* __restrict__ packed)
{
    const int t = blockIdx.x * 256 + threadIdx.x;  // 0 .. 128^3-1
    const int x = t & 127;
    const int y = (t >> 7) & 127;
    const int z = t >> 14;
    const int xp = min(x + 1, 127);
    const int yp = min(y + 1, 127);
    const int zp = min(z + 1, 127);
    const float* p00 = vol + (z  * LSIDE + y ) * LSIDE;
    const float* p01 = vol + (z  * LSIDE + yp) * LSIDE;
    const float* p10 = vol + (zp * LSIDE + y ) * LSIDE;
    const float* p11 = vol + (zp * LSIDE + yp) * LSIDE;
    P8 o;
    o.h[0] = __float2half(p00[x]); o.h[1] = __float2half(p00[xp]);
    o.h[2] = __float2half(p01[x]); o.h[3] = __float2half(p01[xp]);
    o.h[4] = __float2half(p10[x]); o.h[5] = __float2half(p10[xp]);
    o.h[6] = __float2half(p11[x]); o.h[7] = __float2half(p11[xp]);
    packed[t] = o.v;
}

__device__ __forceinline__ void clip1(float r, float c, float A, float B,
                                      float& lo, float& hi)
{
    if (fabsf(r) > 1e-12f) {
        const float inv = 1.0f / r;
        const float a = (A - c) * inv, e = (B - c) * inv;
        lo = fmaxf(lo, fminf(a, e));
        hi = fminf(hi, fmaxf(a, e));
    } else if (c < A || c > B) {
        lo = 1e9f; hi = -1e9f;
    }
}

__device__ __forceinline__ float trilerp8(int4 cv, float wx1, float wy1, float wz1)
{
    P8 c; c.v = cv;
    const float wx0 = 1.0f - wx1, wy0 = 1.0f - wy1, wz0 = 1.0f - wz1;
    const float v000 = __half2float(c.h[0]);
    const float v001 = __half2float(c.h[1]);
    const float v010 = __half2float(c.h[2]);
    const float v011 = __half2float(c.h[3]);
    const float v100 = __half2float(c.h[4]);
    const float v101 = __half2float(c.h[5]);
    const float v110 = __half2float(c.h[6]);
    const float v111 = __half2float(c.h[7]);
    return ((v000 * wx0 + v001 * wx1) * wy0 + (v010 * wx0 + v011 * wx1) * wy1) * wz0
         + ((v100 * wx0 + v101 * wx1) * wy0 + (v110 * wx0 + v111 * wx1) * wy1) * wz1;
}

// exact masked fp32 scalar-gather accumulation over [ks, ke)
#define BOUNDARY_RUN(ks, ke)                                                            \
    if ((ks) < (ke)) {                                                                  \
        float gx = fmaf(fmaf((float)(ks), h, -1.0f), r20, bx) * 63.5f + 63.5f;          \
        float gy = fmaf(fmaf((float)(ks), h, -1.0f), r21, by) * 63.5f + 63.5f;          \
        float gz = fmaf(fmaf((float)(ks), h, -1.0f), r22, bz) * 63.5f + 63.5f;          \
        for (int k = (ks); k < (ke); ++k) {                                             \
            const float fx = floorf(gx), fy = floorf(gy), fz = floorf(gz);              \
            const int x0 = (int)fx, y0 = (int)fy, z0 = (int)fz;                         \
            const float wx1 = gx - fx, wy1 = gy - fy, wz1 = gz - fz;                    \
            const float wx0m = ((unsigned)x0       < LSIDE) ? (1.0f - wx1) : 0.0f;      \
            const float wx1m = ((unsigned)(x0 + 1) < LSIDE) ? wx1 : 0.0f;               \
            const float wy0m = ((unsigned)y0       < LSIDE) ? (1.0f - wy1) : 0.0f;      \
            const float wy1m = ((unsigned)(y0 + 1) < LSIDE) ? wy1 : 0.0f;               \
            const float wz0m = ((unsigned)z0       < LSIDE) ? (1.0f - wz1) : 0.0f;      \
            const float wz1m = ((unsigned)(z0 + 1) < LSIDE) ? wz1 : 0.0f;               \
            const int cx0 = min(max(x0, 0), LSIDE - 1);                                 \
            const int cx1 = min(max(x0 + 1, 0), LSIDE - 1);                             \
            const int cy0 = min(max(y0, 0), LSIDE - 1) * LSIDE;                         \
            const int cy1 = min(max(y0 + 1, 0), LSIDE - 1) * LSIDE;                     \
            const int cz0 = min(max(z0, 0), LSIDE - 1) * LSIDE * LSIDE;                 \
            const int cz1 = min(max(z0 + 1, 0), LSIDE - 1) * LSIDE * LSIDE;             \
            const float v000 = vol[cz0 + cy0 + cx0];                                    \
            const float v001 = vol[cz0 + cy0 + cx1];                                    \
            const float v010 = vol[cz0 + cy1 + cx0];                                    \
            const float v011 = vol[cz0 + cy1 + cx1];                                    \
            const float v100 = vol[cz1 + cy0 + cx0];                                    \
            const float v101 = vol[cz1 + cy0 + cx1];                                    \
            const float v110 = vol[cz1 + cy1 + cx0];                                    \
            const float v111 = vol[cz1 + cy1 + cx1];                                    \
            gx += dxg; gy += dyg; gz += dzg;                                            \
            const float vx00 = v000 * wx0m + v001 * wx1m;                               \
            const float vx01 = v010 * wx0m + v011 * wx1m;                               \
            const float vx10 = v100 * wx0m + v101 * wx1m;                               \
            const float vx11 = v110 * wx0m + v111 * wx1m;                               \
            acc += (vx00 * wy0m + vx01 * wy1m) * wz0m                                   \
                 + (vx10 * wy0m + vx11 * wy1m) * wz1m;                                  \
        }                                                                               \
    }

// interior: ONE dwordx4 gather per sample from packed8 (unroll 2)
#define INTERIOR_RUN(ks, ke)                                                            \
    if ((ks) < (ke)) {                                                                  \
        float gx = fmaf(fmaf((float)(ks), h, -1.0f), r20, bx) * 63.5f + 63.5f;          \
        float gy = fmaf(fmaf((float)(ks), h, -1.0f), r21, by) * 63.5f + 63.5f;          \
        float gz = fmaf(fmaf((float)(ks), h, -1.0f), r22, bz) * 63.5f + 63.5f;          \
        _Pragma("unroll 2")                                                             \
        for (int k = (ks); k < (ke); ++k) {                                             \
            const float fx = floorf(gx), fy = floorf(gy), fz = floorf(gz);              \
            const int x0 = (int)fx, y0 = (int)fy, z0 = (int)fz;                         \
            const float wx1 = gx - fx, wy1 = gy - fy, wz1 = gz - fz;                    \
            const int4 cv = packed[(z0 * LSIDE + y0) * LSIDE + x0];                     \
            gx += dxg; gy += dyg; gz += dzg;                                            \
            acc += trilerp8(cv, wx1, wy1, wz1);                                         \
        }                                                                               \
    }

__global__ __launch_bounds__(256) void ProjectorMultiRes_59236188947236_kernel(
    const float* __restrict__ rotmat,
    const float* __restrict__ vol,
    const int4* __restrict__ packed,
    const float* __restrict__ coords,
    float* __restrict__ out)
{
    __shared__ float lin[LSIDE];
    __shared__ float red[2][64];
    const int tid = threadIdx.x;
    if (tid < LSIDE) lin[tid] = coords[3 * tid + 2];
    __syncthreads();

    // 2048 blocks; XCD-contiguous: XCD x gets logical [x*256,(x+1)*256) = 2 poses
    const int logical = (blockIdx.x & 7) * 256 + (blockIdx.x >> 3);
    const int b = logical >> 7;            // pose
    const int p = logical & 127;           // tile-pair (16 rows x 8 pairs)

    // wave -> 8x8 pixel tile; block = 2 tiles x 2 k-halves
    const int wave    = tid >> 6;
    const int lane    = tid & 63;
    const int tileSel = wave >> 1;         // which tile of the pair
    const int half    = wave & 1;          // k-half
    const int di = lane >> 3;
    const int dj = lane & 7;
    const int i = (p >> 3) * 8 + di;                       // tile row 0..15
    const int j = ((p & 7) * 2 + tileSel) * 8 + dj;        // tile col 0..15

    const float* R = rotmat + b * 9;
    const float r00 = R[0], r01 = R[1], r02 = R[2];
    const float r10 = R[3], r11 = R[4], r12 = R[5];
    const float r20 = R[6], r21 = R[7], r22 = R[8];

    const float lj = lin[j];
    const float li = lin[i];
    const float bx = lj * r00 + li * r10;
    const float by = lj * r01 + li * r11;
    const float bz = lj * r02 + li * r12;

    const float h = 2.0f / 127.0f;

    // outer interval: any-contribution samples
    const float Bd = 1.0f + 1.0f / 63.5f + 1e-4f;
    float lo = -1.0f, hi = 1.0f;
    clip1(r20, bx, -Bd, Bd, lo, hi);
    clip1(r21, by, -Bd, Bd, lo, hi);
    clip1(r22, bz, -Bd, Bd, lo, hi);
    int k0 = max((int)ceilf((lo + 1.0f) / h) - 1, 0);
    int k1 = min((int)floorf((hi + 1.0f) / h) + 2, LSIDE);
    if (k1 < k0) k1 = k0;

    // inner interval: fully-interior samples
    const float AIN = 0.02f / 63.5f - 1.0f;
    const float BIN = 126.98f / 63.5f - 1.0f;
    float loi = -1.0f, hii = 1.0f;
    clip1(r20, bx, AIN, BIN, loi, hii);
    clip1(r21, by, AIN, BIN, loi, hii);
    clip1(r22, bz, AIN, BIN, loi, hii);
    int ia = (int)ceilf((loi + 1.0f) / h) + 1;
    int ib = (int)floorf((hii + 1.0f) / h);
    ia = min(max(ia, k0), k1);
    ib = min(max(ib, ia), k1);

    const float dxg = h * r20 * 63.5f;
    const float dyg = h * r21 * 63.5f;
    const float dzg = h * r22 * 63.5f;

    // split [k0,k1) between the two k-halves
    const int cnt  = k1 - k0;
    const int kmid = k0 + ((cnt + 1) >> 1);
    const int ks = half ? kmid : k0;
    const int ke = half ? k1   : kmid;

    // segment boundaries intersected with [ks,ke)
    const int s1e = min(ke, max(ks, ia));            // boundary prefix
    const int s2s = min(max(ks, ia), ke);
    const int s2e = min(max(ks, ib), ke);            // interior band
    const int s3s = min(ke, max(ks, ib));            // boundary suffix

    float acc = 0.0f;
    BOUNDARY_RUN(ks, s1e)
    INTERIOR_RUN(s2s, s2e)
    BOUNDARY_RUN(s3s, ke)

    if (half) red[tileSel][lane] = acc;
    __syncthreads();
    if (!half)
        out[(b * LSIDE + i) * LSIDE + j] = acc + red[tileSel][lane];
}

extern "C" void kernel_launch(void* const* d_in, const int* in_sizes, int n_in,
                              void* d_out, int out_size, void* d_ws, size_t ws_size,
                              hipStream_t stream) {
    const float* rotmat = (const float*)d_in[0];
    const float* vol    = (const float*)d_in[1];
    const float* coords = (const float*)d_in[2];
    float* out = (float*)d_out;

    int4* packed = (int4*)d_ws;
    pack8_kernel<<<(LSIDE * LSIDE * LSIDE) / 256, 256, 0, stream>>>(vol, packed);
    ProjectorMultiRes_59236188947236_kernel<<<NB * LSIDE, 256, 0, stream>>>(
        rotmat, vol, packed, coords, out);
}

// Round 12
// 92.206 us; speedup vs baseline: 1.2729x; 1.2729x over previous
//
#include <hip/hip_runtime.h>
#include <hip/hip_fp16.h>

#define LSIDE 128
#define NB 16

union P8 { __half h[8]; int4 v; };

// packed8[z][y][x] = fp16 {v000,v001,v010,v011,v100,v101,v110,v111}
// corner pairs: x-pair innermost, then y, then z; edges clamped (xp=min(x+1,127) etc.)
__global__ __launch_bounds__(256) void pack8_kernel(
    const float* __restrict__ vol, int4* __restrict__ packed)
{
    const int t = blockIdx.x * 256 + threadIdx.x;  // 0 .. 128^3-1
    const int x = t & 127;
    const int y = (t >> 7) & 127;
    const int z = t >> 14;
    const int xp = min(x + 1, 127);
    const int yp = min(y + 1, 127);
    const int zp = min(z + 1, 127);
    const float* p00 = vol + (z  * LSIDE + y ) * LSIDE;
    const float* p01 = vol + (z  * LSIDE + yp) * LSIDE;
    const float* p10 = vol + (zp * LSIDE + y ) * LSIDE;
    const float* p11 = vol + (zp * LSIDE + yp) * LSIDE;
    P8 o;
    o.h[0] = __float2half(p00[x]); o.h[1] = __float2half(p00[xp]);
    o.h[2] = __float2half(p01[x]); o.h[3] = __float2half(p01[xp]);
    o.h[4] = __float2half(p10[x]); o.h[5] = __float2half(p10[xp]);
    o.h[6] = __float2half(p11[x]); o.h[7] = __float2half(p11[xp]);
    packed[t] = o.v;
}

__device__ __forceinline__ void clip1(float r, float c, float A, float B,
                                      float& lo, float& hi)
{
    if (fabsf(r) > 1e-12f) {
        const float inv = 1.0f / r;
        const float a = (A - c) * inv, e = (B - c) * inv;
        lo = fmaxf(lo, fminf(a, e));
        hi = fminf(hi, fmaxf(a, e));
    } else if (c < A || c > B) {
        lo = 1e9f; hi = -1e9f;
    }
}

// per-axis clamped-cell weight fixup (zeros padding semantics):
//   x0 == -1      -> cell 0,   weights (wx1, 0)
//   x0 in [0,126] -> cell x0,  weights (wx0, wx1)
//   x0 == 127     -> cell 127, weights (wx0, 0)   [packed corners both = v127]
//   else          -> weights (0, 0)
__device__ __forceinline__ void axis_fix(float g, int& c, float& w0, float& w1)
{
    const float f = floorf(g);
    const int x0 = (int)f;
    const float t1 = g - f;
    const float t0 = 1.0f - t1;
    w0 = ((unsigned)x0 <= 127u) ? t0 : ((x0 == -1) ? t1 : 0.0f);
    w1 = ((unsigned)x0 <= 126u) ? t1 : 0.0f;
    c = min(max(x0, 0), LSIDE - 1);
}

__global__ __launch_bounds__(256) void ProjectorMultiRes_59236188947236_kernel(
    const float* __restrict__ rotmat,
    const int4* __restrict__ packed,
    const float* __restrict__ coords,
    float* __restrict__ out)
{
    __shared__ float lin[LSIDE];
    __shared__ float red[LSIDE];
    const int tid = threadIdx.x;
    if (tid < LSIDE) lin[tid] = coords[3 * tid + 2];
    __syncthreads();

    // 2048 blocks; XCD-contiguous: XCD x gets logical [x*256,(x+1)*256) = 2 poses
    const int logical = (blockIdx.x & 7) * 256 + (blockIdx.x >> 3);
    const int b = logical >> 7;           // pose
    const int i = logical & 127;          // row
    const int j = tid & 127;
    const int half = tid >> 7;            // k-split

    const float* R = rotmat + b * 9;
    const float r00 = R[0], r01 = R[1], r02 = R[2];
    const float r10 = R[3], r11 = R[4], r12 = R[5];
    const float r20 = R[6], r21 = R[7], r22 = R[8];

    const float lj = lin[j];
    const float li = lin[i];
    const float bx = lj * r00 + li * r10;
    const float by = lj * r01 + li * r11;
    const float bz = lj * r02 + li * r12;

    const float h = 2.0f / 127.0f;

    // outer interval: any-contribution samples (index in [-0.02, 127.02])
    const float Bd = 1.0f + 1.0f / 63.5f + 1e-4f;
    float lo = -1.0f, hi = 1.0f;
    clip1(r20, bx, -Bd, Bd, lo, hi);
    clip1(r21, by, -Bd, Bd, lo, hi);
    clip1(r22, bz, -Bd, Bd, lo, hi);
    int k0 = max((int)ceilf((lo + 1.0f) / h) - 1, 0);
    int k1 = min((int)floorf((hi + 1.0f) / h) + 2, LSIDE);
    if (k1 < k0) k1 = k0;

    const float dxg = h * r20 * 63.5f;
    const float dyg = h * r21 * 63.5f;
    const float dzg = h * r22 * 63.5f;

    // split [k0,k1) between the two thread-halves
    const int cnt  = k1 - k0;
    const int kmid = k0 + ((cnt + 1) >> 1);
    const int ks = half ? kmid : k0;
    const int ke = half ? k1   : kmid;

    float gx = fmaf(fmaf((float)ks, h, -1.0f), r20, bx) * 63.5f + 63.5f;
    float gy = fmaf(fmaf((float)ks, h, -1.0f), r21, by) * 63.5f + 63.5f;
    float gz = fmaf(fmaf((float)ks, h, -1.0f), r22, bz) * 63.5f + 63.5f;

    float acc = 0.0f;

    #pragma unroll 2
    for (int k = ks; k < ke; ++k) {
        int cx, cy, cz;
        float w0x, w1x, w0y, w1y, w0z, w1z;
        axis_fix(gx, cx, w0x, w1x);
        axis_fix(gy, cy, w0y, w1y);
        axis_fix(gz, cz, w0z, w1z);

        P8 c;
        c.v = packed[(cz * LSIDE + cy) * LSIDE + cx];
        gx += dxg; gy += dyg; gz += dzg;

        const float v000 = __half2float(c.h[0]);
        const float v001 = __half2float(c.h[1]);
        const float v010 = __half2float(c.h[2]);
        const float v011 = __half2float(c.h[3]);
        const float v100 = __half2float(c.h[4]);
        const float v101 = __half2float(c.h[5]);
        const float v110 = __half2float(c.h[6]);
        const float v111 = __half2float(c.h[7]);
        acc += ((v000 * w0x + v001 * w1x) * w0y + (v010 * w0x + v011 * w1x) * w1y) * w0z
             + ((v100 * w0x + v101 * w1x) * w0y + (v110 * w0x + v111 * w1x) * w1y) * w1z;
    }

    if (half) red[j] = acc;
    __syncthreads();
    if (!half) out[(b * LSIDE + i) * LSIDE + j] = acc + red[j];
}

extern "C" void kernel_launch(void* const* d_in, const int* in_sizes, int n_in,
                              void* d_out, int out_size, void* d_ws, size_t ws_size,
                              hipStream_t stream) {
    const float* rotmat = (const float*)d_in[0];
    const float* vol    = (const float*)d_in[1];
    const float* coords = (const float*)d_in[2];
    float* out = (float*)d_out;

    int4* packed = (int4*)d_ws;
    pack8_kernel<<<(LSIDE * LSIDE * LSIDE) / 256, 256, 0, stream>>>(vol, packed);
    ProjectorMultiRes_59236188947236_kernel<<<NB * LSIDE, 256, 0, stream>>>(
        rotmat, packed, coords, out);
}

// Round 13
// 89.181 us; speedup vs baseline: 1.3161x; 1.0339x over previous
//
#include <hip/hip_runtime.h>
#include <hip/hip_fp16.h>

#define LSIDE 128
#define NB 16

union P8 { __half h[8]; int4 v; };

// packed8[z][y][x] = fp16 {v000,v001,v010,v011,v100,v101,v110,v111}
// corner pairs: x-pair innermost, then y, then z; edges clamped.
__global__ __launch_bounds__(256) void pack8_kernel(
    const float* __restrict__ vol, int4* __restrict__ packed)
{
    const int t = blockIdx.x * 256 + threadIdx.x;  // 0 .. 128^3-1
    const int x = t & 127;
    const int y = (t >> 7) & 127;
    const int z = t >> 14;
    const int xp = min(x + 1, 127);
    const int yp = min(y + 1, 127);
    const int zp = min(z + 1, 127);
    const float* p00 = vol + (z  * LSIDE + y ) * LSIDE;
    const float* p01 = vol + (z  * LSIDE + yp) * LSIDE;
    const float* p10 = vol + (zp * LSIDE + y ) * LSIDE;
    const float* p11 = vol + (zp * LSIDE + yp) * LSIDE;
    P8 o;
    o.h[0] = __float2half(p00[x]); o.h[1] = __float2half(p00[xp]);
    o.h[2] = __float2half(p01[x]); o.h[3] = __float2half(p01[xp]);
    o.h[4] = __float2half(p10[x]); o.h[5] = __float2half(p10[xp]);
    o.h[6] = __float2half(p11[x]); o.h[7] = __float2half(p11[xp]);
    packed[t] = o.v;
}

__device__ __forceinline__ void clip1(float r, float c, float A, float B,
                                      float& lo, float& hi)
{
    if (fabsf(r) > 1e-12f) {
        const float inv = 1.0f / r;
        const float a = (A - c) * inv, e = (B - c) * inv;
        lo = fmaxf(lo, fminf(a, e));
        hi = fminf(hi, fmaxf(a, e));
    } else if (c < A || c > B) {
        lo = 1e9f; hi = -1e9f;
    }
}

// per-axis clamped-cell weight fixup (zeros padding semantics)
__device__ __forceinline__ void axis_fix(float g, int& c, float& w0, float& w1)
{
    const float f = floorf(g);
    const int x0 = (int)f;
    const float t1 = g - f;
    const float t0 = 1.0f - t1;
    w0 = ((unsigned)x0 <= 127u) ? t0 : ((x0 == -1) ? t1 : 0.0f);
    w1 = ((unsigned)x0 <= 126u) ? t1 : 0.0f;
    c = min(max(x0, 0), LSIDE - 1);
}

__global__ __launch_bounds__(256) void ProjectorMultiRes_59236188947236_kernel(
    const float* __restrict__ rotmat,
    const int4* __restrict__ packed,
    const float* __restrict__ coords,
    float* __restrict__ out)
{
    const int tid  = threadIdx.x;
    const int wid  = tid >> 6;       // wave 0..3
    const int lane = tid & 63;
    const int g    = lane >> 3;      // pixel group 0..7 within wave
    const int l    = lane & 7;       // k-slot 0..7 within group

    // 8192 blocks; XCD-contiguous: XCD x gets logical [x*1024,(x+1)*1024) = 2 poses
    const int logical = (blockIdx.x & 7) * 1024 + (blockIdx.x >> 3);
    const int b   = logical >> 9;            // pose (512 blocks per pose)
    const int rem = logical & 511;
    const int i   = rem >> 2;                // row
    const int jc  = rem & 3;                 // 32-col chunk
    const int j   = jc * 32 + wid * 8 + g;   // pixel column

    const float* R = rotmat + b * 9;
    const float r00 = R[0], r01 = R[1], r02 = R[2];
    const float r10 = R[3], r11 = R[4], r12 = R[5];
    const float r20 = R[6], r21 = R[7], r22 = R[8];

    const float lj = coords[3 * j + 2];      // lin[j]
    const float li = coords[3 * i + 2];      // lin[i]
    const float bx = lj * r00 + li * r10;
    const float by = lj * r01 + li * r11;
    const float bz = lj * r02 + li * r12;

    const float h = 2.0f / 127.0f;

    // valid-k interval: any-contribution samples (index in [-0.02, 127.02])
    const float Bd = 1.0f + 1.0f / 63.5f + 1e-4f;
    float lo = -1.0f, hi = 1.0f;
    clip1(r20, bx, -Bd, Bd, lo, hi);
    clip1(r21, by, -Bd, Bd, lo, hi);
    clip1(r22, bz, -Bd, Bd, lo, hi);
    int k0 = max((int)ceilf((lo + 1.0f) / h) - 1, 0);
    int k1 = min((int)floorf((hi + 1.0f) / h) + 2, LSIDE);
    if (k1 < k0) k1 = k0;

    const float dxg = h * r20 * 63.5f;
    const float dyg = h * r21 * 63.5f;
    const float dzg = h * r22 * 63.5f;
    const float sdx = 8.0f * dxg, sdy = 8.0f * dyg, sdz = 8.0f * dzg;

    int k = k0 + l;                          // this lane's k-slots: k0+l, +8, +16, ...
    const float lk = fmaf((float)k, h, -1.0f);
    float gx = fmaf(lk, r20, bx) * 63.5f + 63.5f;
    float gy = fmaf(lk, r21, by) * 63.5f + 63.5f;
    float gz = fmaf(lk, r22, bz) * 63.5f + 63.5f;

    float acc = 0.0f;

    #pragma unroll 2
    for (; k < k1; k += 8) {
        int cx, cy, cz;
        float w0x, w1x, w0y, w1y, w0z, w1z;
        axis_fix(gx, cx, w0x, w1x);
        axis_fix(gy, cy, w0y, w1y);
        axis_fix(gz, cz, w0z, w1z);

        P8 c;
        c.v = packed[(cz * LSIDE + cy) * LSIDE + cx];
        gx += sdx; gy += sdy; gz += sdz;

        const float v000 = __half2float(c.h[0]);
        const float v001 = __half2float(c.h[1]);
        const float v010 = __half2float(c.h[2]);
        const float v011 = __half2float(c.h[3]);
        const float v100 = __half2float(c.h[4]);
        const float v101 = __half2float(c.h[5]);
        const float v110 = __half2float(c.h[6]);
        const float v111 = __half2float(c.h[7]);
        acc += ((v000 * w0x + v001 * w1x) * w0y + (v010 * w0x + v011 * w1x) * w1y) * w0z
             + ((v100 * w0x + v101 * w1x) * w0y + (v110 * w0x + v111 * w1x) * w1y) * w1z;
    }

    // reduce the 8 k-slots of each pixel group
    acc += __shfl_down(acc, 4, 8);
    acc += __shfl_down(acc, 2, 8);
    acc += __shfl_down(acc, 1, 8);
    if (l == 0)
        out[(b * LSIDE + i) * LSIDE + j] = acc;
}

extern "C" void kernel_launch(void* const* d_in, const int* in_sizes, int n_in,
                              void* d_out, int out_size, void* d_ws, size_t ws_size,
                              hipStream_t stream) {
    const float* rotmat = (const float*)d_in[0];
    const float* vol    = (const float*)d_in[1];
    const float* coords = (const float*)d_in[2];
    float* out = (float*)d_out;

    int4* packed = (int4*)d_ws;
    pack8_kernel<<<(LSIDE * LSIDE * LSIDE) / 256, 256, 0, stream>>>(vol, packed);
    ProjectorMultiRes_59236188947236_kernel<<<NB * LSIDE * LSIDE / 32, 256, 0, stream>>>(
        rotmat, packed, coords, out);
}